// Round 2
// 503.704 us; speedup vs baseline: 1.0101x; 1.0101x over previous
//
#include <hip/hip_runtime.h>

// CT-LSTM fused cell. B=1048576, INPUT=64, HIDDEN=16, D=80, 5 gates.
// R3b: swapped-operand MFMA (D comes out transposed -> lane owns one batch row
// x 4 gate-cols) so the epilogue does 1 float4 cprev load + 1 dt load + 2
// nontemporal dwordx4 stores per tile instead of 8 scalar loads + 8 scalar
// stores. W fragments + bias staged in LDS (frees ~60 regs of unified-file
// pressure). Grid fixed at 8192x256 -> exactly 2 tiles/wave, hardcoded, with
// both tiles' global loads issued up front (tile-1 latency hides under tile-0
// compute). (R3 fix: nontemporal stores need ext_vector_type, not HIP float4.)

#define BATCH   1048576
#define NTILES  (BATCH / 16)      // 65536
#define NBLOCKS 8192
#define NWAVES  (NBLOCKS * 4)     // 32768 waves -> 2 tiles/wave exactly
#define L2E     1.442695041f
#define LN2     0.6931471806f

typedef __bf16 bf16x8 __attribute__((ext_vector_type(8)));
typedef float  f32x4  __attribute__((ext_vector_type(4)));

// d_ws layout: [15][64] bf16x8 fragments (chunk = t*3+kt, per-lane 16B),
// then float bias[5][16] at byte offset 15*64*16 = 15360. Total 15680 B.
#define WS_BIAS_OFF 15360
#define WS_BYTES    15680

__device__ __forceinline__ float fast_tanh(float x) {
    float e = __builtin_amdgcn_exp2f(x * (2.0f * L2E));
    return 1.0f - 2.0f * __builtin_amdgcn_rcpf(e + 1.0f);
}

__global__ void pack_w_kernel(const float* __restrict__ Wi, const float* __restrict__ bi,
                              const float* __restrict__ Wf, const float* __restrict__ bf_,
                              const float* __restrict__ Wo, const float* __restrict__ bo,
                              const float* __restrict__ Wc, const float* __restrict__ bc,
                              const float* __restrict__ Wd, const float* __restrict__ bd,
                              void* __restrict__ ws)
{
    const float* W[5]  = {Wi, Wf, Wo, Wc, Wd};
    const float* BP[5] = {bi, bf_, bo, bc, bd};
    const int b    = blockIdx.x;      // 0..14 = W chunks, 15 = bias
    const int lane = threadIdx.x;     // 64 threads
    if (b < 15) {
        const int t = b / 3, kt = b % 3;
        const int quad = lane >> 4, col = lane & 15;
        bf16x8 f;
        #pragma unroll
        for (int j = 0; j < 8; ++j) {
            int k = kt * 32 + quad * 8 + j;
            float v = (k < 80) ? W[t][k * 16 + col] : 0.0f;  // zero-pad K 80->96
            f[j] = (__bf16)v;
        }
        ((bf16x8*)ws)[b * 64 + lane] = f;
    } else {
        if (lane < 80) {
            int t = lane >> 4, col = lane & 15;
            ((float*)((char*)ws + WS_BIAS_OFF))[lane] = BP[t][col];
        }
    }
}

__global__ __launch_bounds__(256, 4)
void ctlstm_kernel(const float* __restrict__ x,
                   const float* __restrict__ hprev,
                   const float* __restrict__ cprev,
                   const float* __restrict__ dt,
                   const void* __restrict__ ws,
                   float* __restrict__ out)
{
    __shared__ __align__(16) char smem[WS_BYTES];
    const int tid = threadIdx.x;

    // ---- one-time stage: ws (W frags + bias) -> LDS ----
    {
        const float4* src = (const float4*)ws;
        float4*       dst = (float4*)smem;
        #pragma unroll
        for (int i = 0; i < 4; ++i) {
            int idx = tid + i * 256;
            if (idx < WS_BYTES / 16) dst[idx] = src[idx];
        }
    }
    __syncthreads();

    const int lane = tid & 63;
    const int col  = lane & 15;   // batch row within tile (D col, swapped)
    const int quad = lane >> 4;   // gate-col group (D row group, swapped)

    // bias: lane reg r needs b[t*16 + quad*4 + r] -> one broadcast float4 per t
    float4 b4[5];
    #pragma unroll
    for (int t = 0; t < 5; ++t)
        b4[t] = *(const float4*)(smem + WS_BIAS_OFF + t * 64 + quad * 16);

    const int gw = (blockIdx.x * 256 + tid) >> 6;  // 0..32767

    const float4* X4 = (const float4*)x;      // [B][16] float4 per row
    const float4* H4 = (const float4*)hprev;  // [B][4]  float4 per row
    const float4* C4 = (const float4*)cprev;  // [B][4]  float4 per row

    const int arow0 = (gw << 4) + col;             // tile 0: lane's batch row
    const int arow1 = ((gw + NWAVES) << 4) + col;  // tile 1

    // ---- issue ALL global loads for both tiles up front ----
    float4 a0 = X4[arow0 * 16 + quad * 2];
    float4 a1 = X4[arow0 * 16 + quad * 2 + 1];
    float4 a2 = X4[arow0 * 16 + quad * 2 + 8];
    float4 a3 = X4[arow0 * 16 + quad * 2 + 9];
    float4 cv0 = C4[arow0 * 4 + quad];             // cprev[row][quad*4..+3]
    float  dv0 = dt[arow0];

    float4 g0 = X4[arow1 * 16 + quad * 2];
    float4 g1 = X4[arow1 * 16 + quad * 2 + 1];
    float4 g2 = X4[arow1 * 16 + quad * 2 + 8];
    float4 g3 = X4[arow1 * 16 + quad * 2 + 9];
    float4 cv1 = C4[arow1 * 4 + quad];
    float  dv1 = dt[arow1];

    float4 a4 = make_float4(0.f, 0.f, 0.f, 0.f), a5 = a4;
    float4 g4 = a4, g5 = a4;
    if (quad < 2) {   // k = 64..79 (h_prev); quads 2,3 stay zero (pad 80->96)
        a4 = H4[arow0 * 4 + quad * 2];
        a5 = H4[arow0 * 4 + quad * 2 + 1];
        g4 = H4[arow1 * 4 + quad * 2];
        g5 = H4[arow1 * 4 + quad * 2 + 1];
    }

    const bf16x8* WF = (const bf16x8*)smem;

    auto process = [&](int arow,
                       const float4& p0, const float4& p1, const float4& p2,
                       const float4& p3, const float4& p4, const float4& p5,
                       const float4& cp4, float dtv) {
        // pack A (= combined^T as the B-operand of the swapped MFMA)
        bf16x8 A0, A1, A2;
        #pragma unroll
        for (int j = 0; j < 4; ++j) {
            A0[j]     = (__bf16)((const float*)&p0)[j];
            A0[j + 4] = (__bf16)((const float*)&p1)[j];
            A1[j]     = (__bf16)((const float*)&p2)[j];
            A1[j + 4] = (__bf16)((const float*)&p3)[j];
            A2[j]     = (__bf16)((const float*)&p4)[j];
            A2[j + 4] = (__bf16)((const float*)&p5)[j];
        }

        // swapped operands: D = W^T * combined^T -> lane owns
        // (batch row = arow, gate cols quad*4 + r). Bias rides in as C-init.
        f32x4 acc[5];
        #pragma unroll
        for (int t = 0; t < 5; ++t) {
            f32x4 c0 = {b4[t].x, b4[t].y, b4[t].z, b4[t].w};
            c0 = __builtin_amdgcn_mfma_f32_16x16x32_bf16(WF[(t * 3 + 0) * 64 + lane], A0, c0, 0, 0, 0);
            c0 = __builtin_amdgcn_mfma_f32_16x16x32_bf16(WF[(t * 3 + 1) * 64 + lane], A1, c0, 0, 0, 0);
            acc[t] = __builtin_amdgcn_mfma_f32_16x16x32_bf16(WF[(t * 3 + 2) * 64 + lane], A2, c0, 0, 0, 0);
        }

        // ---- epilogue: lane owns row=arow, cols quad*4 .. quad*4+3 ----
        f32x4 hn4, cn4;
        #pragma unroll
        for (int r = 0; r < 4; ++r) {
            float zi = acc[0][r], zf = acc[1][r], zo = acc[2][r];
            float zc = acc[3][r], zd = acc[4][r];

            float i_g = fast_tanh(zi);
            float f_g = fast_tanh(zf);
            float o_g = fast_tanh(zo);
            float ctl = fast_tanh(zc);

            // softplus(zd) = max(zd,0) + ln(1 + e^{-|zd|})
            float ax = fabsf(zd);
            float e  = __builtin_amdgcn_exp2f(-ax * L2E);
            float sp = fmaxf(zd, 0.0f) + __builtin_amdgcn_logf(1.0f + e) * LN2;

            float cdec = ((const float*)&cp4)[r] * __builtin_amdgcn_exp2f(-sp * dtv * L2E);
            float cn   = f_g * cdec + i_g * ctl;
            float hn   = o_g * fast_tanh(cn);

            hn4[r] = hn;
            cn4[r] = cn;
        }
        __builtin_nontemporal_store(hn4, (f32x4*)(out + (size_t)arow * 16 + quad * 4));
        __builtin_nontemporal_store(cn4, (f32x4*)(out + (size_t)BATCH * 16 + (size_t)arow * 16 + quad * 4));
    };

    process(arow0, a0, a1, a2, a3, a4, a5, cv0, dv0);
    process(arow1, g0, g1, g2, g3, g4, g5, cv1, dv1);
}

extern "C" void kernel_launch(void* const* d_in, const int* in_sizes, int n_in,
                              void* d_out, int out_size, void* d_ws, size_t ws_size,
                              hipStream_t stream) {
    pack_w_kernel<<<16, 64, 0, stream>>>(
        (const float*)d_in[4],  (const float*)d_in[5],
        (const float*)d_in[6],  (const float*)d_in[7],
        (const float*)d_in[8],  (const float*)d_in[9],
        (const float*)d_in[10], (const float*)d_in[11],
        (const float*)d_in[12], (const float*)d_in[13],
        d_ws);
    ctlstm_kernel<<<NBLOCKS, 256, 0, stream>>>(
        (const float*)d_in[0], (const float*)d_in[1],
        (const float*)d_in[2], (const float*)d_in[3],
        d_ws, (float*)d_out);
}

// Round 3
// 502.220 us; speedup vs baseline: 1.0131x; 1.0030x over previous
//
#include <hip/hip_runtime.h>

// CT-LSTM fused cell. B=1048576, INPUT=64, HIDDEN=16, D=80, 5 gates.
// R4: fix vector-memory TRANSACTION bound. R2/R3b both sat at 162us/dispatch
// with VALUBusy 17%, HBM 2.1 TB/s (33%) -> neither issue- nor byte-bound; the
// invariant was the row-scattered A-fragment loads (lane stride 256B -> 1-2
// lanes per 64B line, ~64 line-txns per instr). Now ALL global loads are
// lane-contiguous (lane i <- base + i*16, 4 lanes/line), and the MFMA A-frags
// are rebuilt through a per-wave-private LDS round-trip: cvt to bf16 pairs ->
// ds_write_b64 into fragment-layout [kt][quad][row][j] with XOR granule
// swizzle (g ^= (q&1)<<2; bank-balanced to the LDS minimum on both sides) ->
// 3x ds_read_b128 per tile. Wave-private buffer => no __syncthreads, lgkmcnt
// ordering only. 2 tiles/wave, both tiles' global loads issued up front.

#define BATCH   1048576
#define NBLOCKS 8192
#define NWAVES  (NBLOCKS * 4)     // 32768 waves -> 2 tiles/wave exactly
#define L2E     1.442695041f
#define LN2     0.6931471806f

typedef __bf16 bf16x8 __attribute__((ext_vector_type(8)));
typedef float  f32x4  __attribute__((ext_vector_type(4)));
typedef unsigned int u32;

// d_ws layout: [15][64] bf16x8 W fragments (chunk = t*3+kt, per-lane 16B),
// then float bias[5][16] at byte offset 15*64*16 = 15360. Total 15680 B.
#define WS_BIAS_OFF 15360
#define WS_BYTES    15680

__device__ __forceinline__ float fast_tanh(float x) {
    float e = __builtin_amdgcn_exp2f(x * (2.0f * L2E));
    return 1.0f - 2.0f * __builtin_amdgcn_rcpf(e + 1.0f);
}

__device__ __forceinline__ u32 pkbf(float a, float b) {
    union { __bf16 h[2]; u32 u; } v;
    v.h[0] = (__bf16)a;
    v.h[1] = (__bf16)b;
    return v.u;
}

__global__ void pack_w_kernel(const float* __restrict__ Wi, const float* __restrict__ bi,
                              const float* __restrict__ Wf, const float* __restrict__ bf_,
                              const float* __restrict__ Wo, const float* __restrict__ bo,
                              const float* __restrict__ Wc, const float* __restrict__ bc,
                              const float* __restrict__ Wd, const float* __restrict__ bd,
                              void* __restrict__ ws)
{
    const float* W[5]  = {Wi, Wf, Wo, Wc, Wd};
    const float* BP[5] = {bi, bf_, bo, bc, bd};
    const int b    = blockIdx.x;      // 0..14 = W chunks, 15 = bias
    const int lane = threadIdx.x;     // 64 threads
    if (b < 15) {
        const int t = b / 3, kt = b % 3;
        const int quad = lane >> 4, col = lane & 15;
        bf16x8 f;
        #pragma unroll
        for (int j = 0; j < 8; ++j) {
            int k = kt * 32 + quad * 8 + j;
            float v = (k < 80) ? W[t][k * 16 + col] : 0.0f;  // zero-pad K 80->96
            f[j] = (__bf16)v;
        }
        ((bf16x8*)ws)[b * 64 + lane] = f;
    } else {
        if (lane < 80) {
            int t = lane >> 4, col = lane & 15;
            ((float*)((char*)ws + WS_BIAS_OFF))[lane] = BP[t][col];
        }
    }
}

__global__ __launch_bounds__(256, 4)
void ctlstm_kernel(const float* __restrict__ x,
                   const float* __restrict__ hprev,
                   const float* __restrict__ cprev,
                   const float* __restrict__ dt,
                   const void* __restrict__ ws,
                   float* __restrict__ out)
{
    __shared__ __align__(16) char smem[WS_BYTES];
    // per-wave tile scratch: 512 dw X-frags + 128 dw H-frags = 2560 B/wave
    __shared__ __align__(16) u32 tilebuf[4][640];
    const int tid = threadIdx.x;

    // ---- one-time stage: ws (W frags + bias) -> LDS ----
    {
        const float4* src = (const float4*)ws;
        float4*       dst = (float4*)smem;
        #pragma unroll
        for (int i = 0; i < 4; ++i) {
            int idx = tid + i * 256;
            if (idx < WS_BYTES / 16) dst[idx] = src[idx];
        }
    }
    __syncthreads();

    const int lane = tid & 63;
    const int wid  = tid >> 6;
    const int col  = lane & 15;   // lane's batch row within tile (swapped MFMA)
    const int quad = lane >> 4;   // lane's gate-col group
    u32* tb = tilebuf[wid];

    // bias: lane reg r needs b[t*16 + quad*4 + r] -> one broadcast float4 per t
    float4 b4[5];
    #pragma unroll
    for (int t = 0; t < 5; ++t)
        b4[t] = *(const float4*)(smem + WS_BIAS_OFF + t * 64 + quad * 16);

    const int gw = (blockIdx.x * 256 + tid) >> 6;  // 0..32767
    const int T0 = gw, T1 = gw + NWAVES;
    const int ar0 = (T0 << 4) + col;
    const int ar1 = (T1 << 4) + col;

    const float4* X4 = (const float4*)x;      // tile = 256 float4 (16 rows x 64f)
    const float4* H4 = (const float4*)hprev;  // tile = 64 float4  (16 rows x 16f)
    const float4* C4 = (const float4*)cprev;

    // ---- issue ALL global loads for both tiles up front, lane-contiguous ----
    float4 xa[4], xb[4];
    #pragma unroll
    for (int L = 0; L < 4; ++L) xa[L] = X4[T0 * 256 + L * 64 + lane];
    float4 ha  = H4[T0 * 64 + lane];
    float4 cva = C4[ar0 * 4 + quad];
    float  dva = dt[ar0];
    #pragma unroll
    for (int L = 0; L < 4; ++L) xb[L] = X4[T1 * 256 + L * 64 + lane];
    float4 hb  = H4[T1 * 64 + lane];
    float4 cvb = C4[ar1 * 4 + quad];
    float  dvb = dt[ar1];

    // per-lane staging coords: lane holds float4 #c4 of its row ->
    // bf16-pairs p0=(c4*2), p0+1 -> slot (kt, q, row, j), j = p0&3 (even)
    const int wkt = (lane >> 3) & 1;        // pair p0 >> 4
    const int wq  = (lane & 7) >> 1;        // (p0 & 15) >> 2
    const int wj  = (lane & 1) * 2;         // p0 & 3
    const int wrb = lane >> 4;              // row = L*4 + wrb
    const int hq  = (lane & 3) >> 1;        // H: pair p0 = (lane&3)*2 -> quad
    const int hrow = lane >> 2;

    // read addresses (granule-swizzled, byte = g*16)
    const int swz = (quad & 1) << 2;
    const int gr0 = (((0 * 4 + quad) * 16 + col) ^ swz) * 4;
    const int gr1 = (((1 * 4 + quad) * 16 + col) ^ swz) * 4;
    const int gr2 = 512 + ((quad & 1) * 16 + col) * 4;

    const bf16x8* WF = (const bf16x8*)smem;

    auto process = [&](int arow, const float4* xv, const float4& hv,
                       const float4& cp4, float dtv) {
        // ---- stage held data -> LDS in fragment order (bf16 pairs) ----
        #pragma unroll
        for (int L = 0; L < 4; ++L) {
            int row = L * 4 + wrb;
            int g = ((wkt * 4 + wq) * 16 + row) ^ ((wq & 1) << 2);
            uint2 d;
            d.x = pkbf(xv[L].x, xv[L].y);
            d.y = pkbf(xv[L].z, xv[L].w);
            *(uint2*)&tb[g * 4 + wj] = d;   // ds_write_b64
        }
        {
            uint2 d;
            d.x = pkbf(hv.x, hv.y);
            d.y = pkbf(hv.z, hv.w);
            *(uint2*)&tb[512 + (hq * 16 + hrow) * 4 + wj] = d;
        }

        // ---- read A-fragments (3x ds_read_b128) ----
        bf16x8 A0 = *(const bf16x8*)&tb[gr0];
        bf16x8 A1 = *(const bf16x8*)&tb[gr1];
        uint4 a2u = *(const uint4*)&tb[gr2];
        if (quad >= 2) { a2u.x = 0; a2u.y = 0; a2u.z = 0; a2u.w = 0; } // k pad 80->96
        bf16x8 A2 = *(const bf16x8*)&a2u;

        // swapped operands: D = W^T * combined^T -> lane owns
        // (batch row = arow, gate cols quad*4 + r). Bias rides in as C-init.
        f32x4 acc[5];
        #pragma unroll
        for (int t = 0; t < 5; ++t) {
            f32x4 c0 = {b4[t].x, b4[t].y, b4[t].z, b4[t].w};
            c0 = __builtin_amdgcn_mfma_f32_16x16x32_bf16(WF[(t * 3 + 0) * 64 + lane], A0, c0, 0, 0, 0);
            c0 = __builtin_amdgcn_mfma_f32_16x16x32_bf16(WF[(t * 3 + 1) * 64 + lane], A1, c0, 0, 0, 0);
            acc[t] = __builtin_amdgcn_mfma_f32_16x16x32_bf16(WF[(t * 3 + 2) * 64 + lane], A2, c0, 0, 0, 0);
        }

        // ---- epilogue: lane owns row=arow, cols quad*4 .. quad*4+3 ----
        f32x4 hn4, cn4;
        #pragma unroll
        for (int r = 0; r < 4; ++r) {
            float zi = acc[0][r], zf = acc[1][r], zo = acc[2][r];
            float zc = acc[3][r], zd = acc[4][r];

            float i_g = fast_tanh(zi);
            float f_g = fast_tanh(zf);
            float o_g = fast_tanh(zo);
            float ctl = fast_tanh(zc);

            // softplus(zd) = max(zd,0) + ln(1 + e^{-|zd|})
            float ax = fabsf(zd);
            float e  = __builtin_amdgcn_exp2f(-ax * L2E);
            float sp = fmaxf(zd, 0.0f) + __builtin_amdgcn_logf(1.0f + e) * LN2;

            float cdec = ((const float*)&cp4)[r] * __builtin_amdgcn_exp2f(-sp * dtv * L2E);
            float cn   = f_g * cdec + i_g * ctl;
            float hn   = o_g * fast_tanh(cn);

            hn4[r] = hn;
            cn4[r] = cn;
        }
        __builtin_nontemporal_store(hn4, (f32x4*)(out + (size_t)arow * 16 + quad * 4));
        __builtin_nontemporal_store(cn4, (f32x4*)(out + (size_t)BATCH * 16 + (size_t)arow * 16 + quad * 4));
    };

    process(ar0, xa, ha, cva, dva);
    process(ar1, xb, hb, cvb, dvb);
}

extern "C" void kernel_launch(void* const* d_in, const int* in_sizes, int n_in,
                              void* d_out, int out_size, void* d_ws, size_t ws_size,
                              hipStream_t stream) {
    pack_w_kernel<<<16, 64, 0, stream>>>(
        (const float*)d_in[4],  (const float*)d_in[5],
        (const float*)d_in[6],  (const float*)d_in[7],
        (const float*)d_in[8],  (const float*)d_in[9],
        (const float*)d_in[10], (const float*)d_in[11],
        (const float*)d_in[12], (const float*)d_in[13],
        d_ws);
    ctlstm_kernel<<<NBLOCKS, 256, 0, stream>>>(
        (const float*)d_in[0], (const float*)d_in[1],
        (const float*)d_in[2], (const float*)d_in[3],
        d_ws, (float*)d_out);
}